// Round 6
// baseline (639.376 us; speedup 1.0000x reference)
//
#include <hip/hip_runtime.h>

typedef _Float16 f16;
typedef _Float16 f16x2 __attribute__((ext_vector_type(2)));
typedef _Float16 f16x4 __attribute__((ext_vector_type(4)));
typedef _Float16 f16x8 __attribute__((ext_vector_type(8)));
typedef __fp16   h16x2 __attribute__((ext_vector_type(2)));
typedef float    f32x4 __attribute__((ext_vector_type(4)));
typedef f16x8 f16x8_a __attribute__((may_alias));
typedef f16   f16_a   __attribute__((may_alias));

#define NN 100000
#define NE 1000000
#define NT_TILES 31250        // NE/32
#define EK_BLOCKS 256
#define NWAVES (EK_BLOCKS * 8)

static __device__ __forceinline__ f32x4 mfma16(f16x8 a, f16x8 b, f32x4 c) {
  return __builtin_amdgcn_mfma_f32_16x16x32_f16(a, b, c, 0, 0, 0);
}

static __device__ __forceinline__ f16x2 pkrtz(float a, float b) {
  h16x2 r = __builtin_amdgcn_cvt_pkrtz(a, b);
  return __builtin_bit_cast(f16x2, r);
}

static __device__ __forceinline__ f16x8 zero8() {
  f16x8 z;
#pragma unroll
  for (int j = 0; j < 8; ++j) z[j] = (f16)0.f;
  return z;
}

static __device__ __forceinline__ f16x8 cvt8(f32x4 x0, f32x4 x1) {
  f16x8 t;
  t[0]=(f16)x0[0]; t[1]=(f16)x0[1]; t[2]=(f16)x0[2]; t[3]=(f16)x0[3];
  t[4]=(f16)x1[0]; t[5]=(f16)x1[1]; t[6]=(f16)x1[2]; t[7]=(f16)x1[3];
  return t;
}

// assemble B-fragment from 4 packed f16x2 (register relabel, no data movement)
static __device__ __forceinline__ f16x8 frag4(f16x2 a, f16x2 b, f16x2 c, f16x2 d) {
  f16x4 lo = __builtin_shufflevector(a, b, 0, 1, 2, 3);
  f16x4 hi = __builtin_shufflevector(c, d, 0, 1, 2, 3);
  return __builtin_shufflevector(lo, hi, 0, 1, 2, 3, 4, 5, 6, 7);
}

// ---- LDS staging with XOR swizzle (byte ^= (row&7)<<4) ----
template<int RB_LOG2, int SZ, int NTH>
static __device__ __forceinline__ void load_weights(const f16* __restrict__ gw, char* lds) {
  const char* src = (const char*)gw;
#pragma unroll
  for (int g = threadIdx.x; g < SZ / 16; g += NTH) {
    int byte = g << 4;
    int row  = byte >> RB_LOG2;
    int dstb = byte ^ ((row & 7) << 4);
    f16x8 v = *(const f16x8_a*)(src + byte);
    *(f16x8_a*)(lds + dstb) = v;
  }
}

template<int RB_LOG2>
static __device__ __forceinline__ f16x8 read_b(const char* lds, int n, int kbyte) {
  int byte = ((n << RB_LOG2) + kbyte) ^ ((n & 7) << 4);
  return *(const f16x8_a*)(lds + byte);
}

// per-wave activation tile (node kernel only): 32 rows x 128 f16, swizzled
static __device__ __forceinline__ f16x8 act_read(const char* act, int base, int m, int kbyte) {
  int byte = (base + m * 256 + kbyte) ^ ((m & 7) << 4);
  return *(const f16x8_a*)(act + byte);
}

static __device__ __forceinline__ void act_write(char* act, int base, int m, int col, f16 v) {
  int byte = (base + m * 256 + col * 2) ^ ((m & 7) << 4);
  *(f16_a*)(act + byte) = v;
}

// K-permutation for pk-relabel consumers (wc, wp2): F = 32ks + 16a + 4g + b
static __device__ __forceinline__ int kperm(int kk) {
  return 32 * (kk >> 5) + 16 * ((kk >> 2) & 1) + 4 * ((kk >> 3) & 3) + (kk & 3);
}

// ---------------- prep kernels ----------------
__global__ void prep_transpose(const float* __restrict__ Wn1, const float* __restrict__ Wn2,
                               const float* __restrict__ We1, const float* __restrict__ be1,
                               const float* __restrict__ Wp1, const float* __restrict__ Wp2,
                               f16* __restrict__ WnT1, f16* __restrict__ WnT2,
                               f16* __restrict__ WeT1, f16* __restrict__ WaT,
                               f16* __restrict__ WbT,  f16* __restrict__ WpT2) {
  int b = blockIdx.x, t = threadIdx.x;
  if (b < 64)       { int i = b * 256 + t;         int n = i >> 7, k = i & 127; WnT1[i] = (f16)Wn1[(size_t)k * 128 + n]; }
  else if (b < 128) { int i = (b - 64) * 256 + t;  int n = i >> 7, k = i & 127; WnT2[i] = (f16)Wn2[(size_t)k * 128 + n]; }
  else if (b < 160) { int i = (b - 128) * 256 + t; int n = i >> 5, k = i & 31;
                      float v = k < 16 ? We1[(size_t)k * 128 + n] : (k == 16 ? be1[n] : 0.f);
                      WeT1[i] = (f16)v; }
  else if (b < 224) { int i = (b - 160) * 256 + t; int n = i >> 7, k = i & 127; WaT[i] = (f16)Wp1[(size_t)k * 128 + n]; }
  else if (b < 288) { int i = (b - 224) * 256 + t; int n = i >> 7, k = i & 127; WbT[i] = (f16)Wp1[(size_t)(128 + k) * 128 + n]; }
  else              { int i = (b - 288) * 256 + t; int n = i >> 7, kk = i & 127;
                      WpT2[i] = (f16)Wp2[(size_t)kperm(kk) * 64 + n]; }
}

// WC = We2 @ Wp1c (k-permuted, transposed), bfold = bp1 + bn2@(Wp1a+Wp1b) + be2@Wp1c
__global__ void prep_fold(const float* __restrict__ We2, const float* __restrict__ Wp1,
                          const float* __restrict__ bp1, const float* __restrict__ bn2,
                          const float* __restrict__ be2, f16* __restrict__ WCT,
                          float* __restrict__ bfold) {
  int b = blockIdx.x, t = threadIdx.x;
  if (b < 64) {
    int i = b * 256 + t;
    int n = i >> 7, kk = i & 127;
    int F = kperm(kk);
    float s = 0.f;
#pragma unroll 8
    for (int m = 0; m < 128; ++m)
      s += We2[(size_t)F * 128 + m] * Wp1[(size_t)(256 + m) * 128 + n];
    WCT[i] = (f16)s;
  } else if (t < 128) {
    float s = bp1[t];
#pragma unroll 8
    for (int k = 0; k < 128; ++k)
      s += bn2[k] * (Wp1[(size_t)k * 128 + t] + Wp1[(size_t)(128 + k) * 128 + t]);
#pragma unroll 8
    for (int k = 0; k < 128; ++k)
      s += be2[k] * Wp1[(size_t)(256 + k) * 128 + t];
    bfold[t] = s;
  }
}

// ---------------- node encoder: nf -> relu(@Wn1+bn1) -> @Wn2+bn2 -> emb (f16) ----------------
__global__ __launch_bounds__(256, 2) void node_kernel(
    const float* __restrict__ nf, const f16* __restrict__ WnT1, const float* __restrict__ bn1,
    const f16* __restrict__ WnT2, const float* __restrict__ bn2, f16* __restrict__ emb) {
  __shared__ char wbuf[32768];
  __shared__ char act[32768];
  const int tid = threadIdx.x, w = tid >> 6, lane = tid & 63;
  const int c = lane & 15, kb = lane >> 4;
  const int base = blockIdx.x * 128 + w * 32;
  const int abase = w * 8192;

  load_weights<8, 32768, 256>(WnT1, wbuf);
  __syncthreads();

  {
    f16x8 a[2][4];
#pragma unroll
    for (int rt = 0; rt < 2; ++rt) {
      int r = base + rt * 16 + c; r = r < NN ? r : 0;
      const f32x4* p = (const f32x4*)(nf + (size_t)r * 128 + kb * 8);
#pragma unroll
      for (int ks = 0; ks < 4; ++ks) {
        f32x4 x0 = __builtin_nontemporal_load(p + ks * 8);
        f32x4 x1 = __builtin_nontemporal_load(p + ks * 8 + 1);
        a[rt][ks] = cvt8(x0, x1);
      }
    }
    f32x4 acc[2][8];
#pragma unroll
    for (int nt = 0; nt < 8; ++nt) {
      float bb = bn1[nt * 16 + c];
      acc[0][nt] = f32x4{bb, bb, bb, bb};
      acc[1][nt] = f32x4{bb, bb, bb, bb};
    }
#pragma unroll
    for (int ks = 0; ks < 4; ++ks)
#pragma unroll
      for (int nt = 0; nt < 8; ++nt) {
        f16x8 b = read_b<8>(wbuf, nt * 16 + c, ks * 64 + kb * 16);
        acc[0][nt] = mfma16(a[0][ks], b, acc[0][nt]);
        acc[1][nt] = mfma16(a[1][ks], b, acc[1][nt]);
      }
#pragma unroll
    for (int rt = 0; rt < 2; ++rt)
#pragma unroll
      for (int nt = 0; nt < 8; ++nt)
#pragma unroll
        for (int r = 0; r < 4; ++r) {
          float v = acc[rt][nt][r];
          v = v > 0.f ? v : 0.f;
          act_write(act, abase, rt * 16 + kb * 4 + r, nt * 16 + c, (f16)v);
        }
  }

  __syncthreads();
  load_weights<8, 32768, 256>(WnT2, wbuf);
  __syncthreads();

  {
    f32x4 acc[2][8];
#pragma unroll
    for (int nt = 0; nt < 8; ++nt) {
      float bb = bn2[nt * 16 + c];
      acc[0][nt] = f32x4{bb, bb, bb, bb};
      acc[1][nt] = f32x4{bb, bb, bb, bb};
    }
#pragma unroll
    for (int ks = 0; ks < 4; ++ks) {
      f16x8 a0 = act_read(act, abase, c,      ks * 64 + kb * 16);
      f16x8 a1 = act_read(act, abase, 16 + c, ks * 64 + kb * 16);
#pragma unroll
      for (int nt = 0; nt < 8; ++nt) {
        f16x8 b = read_b<8>(wbuf, nt * 16 + c, ks * 64 + kb * 16);
        acc[0][nt] = mfma16(a0, b, acc[0][nt]);
        acc[1][nt] = mfma16(a1, b, acc[1][nt]);
      }
    }
#pragma unroll
    for (int rt = 0; rt < 2; ++rt)
#pragma unroll
      for (int nt = 0; nt < 8; ++nt)
#pragma unroll
        for (int r = 0; r < 4; ++r) {
          int row = base + rt * 16 + kb * 4 + r;
          if (row < NN) emb[(size_t)row * 128 + nt * 16 + c] = (f16)acc[rt][nt][r];
        }
  }
}

// ---------------- persistent fused edge kernel: swapped MFMA, register-chained ----------------
__global__ __launch_bounds__(512, 2) void edge_kernel(
    const float* __restrict__ ef, const int* __restrict__ eidx,
    const f16* __restrict__ We1g, const f16* __restrict__ WaTg,
    const f16* __restrict__ WbTg, const f16* __restrict__ WCTg,
    const f16* __restrict__ Wp2Tg, const float* __restrict__ bfold,
    const float* __restrict__ bp2, const float* __restrict__ Wp3,
    const float* __restrict__ bp3, const f16* __restrict__ emb,
    float* __restrict__ out) {
  __shared__ char wa[32768];
  __shared__ char wb[32768];
  __shared__ char wc[32768];
  __shared__ char wp2l[16384];
  __shared__ char w1l[8192];
  __shared__ float biasl[256];   // [0:128) bfold, [128:192) bp2, [192:256) Wp3
  const int tid = threadIdx.x, w = tid >> 6, lane = tid & 63;
  const int c = lane & 15, kb = lane >> 4;

  load_weights<8, 32768, 512>(WaTg, wa);
  load_weights<8, 32768, 512>(WbTg, wb);
  load_weights<8, 32768, 512>(WCTg, wc);
  load_weights<8, 16384, 512>(Wp2Tg, wp2l);
  load_weights<6, 8192, 512>(We1g, w1l);
  if (tid < 256) {
    float v = tid < 128 ? bfold[tid] : (tid < 192 ? bp2[tid - 128] : Wp3[tid - 192]);
    biasl[tid] = v;
  }
  __syncthreads();   // only barrier

  const float b3 = bp3[0];
  const int gw = blockIdx.x * 8 + w;
  const volatile float* biasv = biasl;

  int sN[2], dN[2];
  f32x4 efN[2][2];

  auto LOAD_IDX = [&](int t) {
#pragma unroll
    for (int et = 0; et < 2; ++et) {
      sN[et] = __builtin_nontemporal_load(eidx + t * 32 + et * 16 + c);
      dN[et] = __builtin_nontemporal_load(eidx + NE + t * 32 + et * 16 + c);
    }
  };
  auto LOAD_EF = [&](int t) {
    if (kb < 2) {
#pragma unroll
      for (int et = 0; et < 2; ++et) {
        const f32x4* p = (const f32x4*)(ef + (size_t)(t * 32 + et * 16 + c) * 16 + kb * 8);
        efN[et][0] = __builtin_nontemporal_load(p);
        efN[et][1] = __builtin_nontemporal_load(p + 1);
      }
    }
  };

  if (gw < NT_TILES) { LOAD_IDX(gw); LOAD_EF(gw); }

  for (int t = gw; t < NT_TILES; t += NWAVES) {
    const int sA0 = sN[0], sA1 = sN[1], dA0 = dN[0], dA1 = dN[1];
    f32x4 efA[2][2] = {{efN[0][0], efN[0][1]}, {efN[1][0], efN[1][1]}};

    // issue this tile's gathers (consumed at P1a/P1b, ~100 MFMAs later)
    f16x8 ga[2][4], gb[2][4];
    {
      const f16* p0 = emb + (size_t)sA0 * 128 + kb * 8;
      const f16* p1 = emb + (size_t)sA1 * 128 + kb * 8;
      const f16* q0 = emb + (size_t)dA0 * 128 + kb * 8;
      const f16* q1 = emb + (size_t)dA1 * 128 + kb * 8;
#pragma unroll
      for (int ks = 0; ks < 4; ++ks) {
        ga[0][ks] = *(const f16x8_a*)(p0 + ks * 32);
        ga[1][ks] = *(const f16x8_a*)(p1 + ks * 32);
        gb[0][ks] = *(const f16x8_a*)(q0 + ks * 32);
        gb[1][ks] = *(const f16x8_a*)(q1 + ks * 32);
      }
    }

    // prefetch next tile's idx + ef
    int tn = t + NWAVES; if (tn >= NT_TILES) tn = t;
    LOAD_IDX(tn);
    LOAD_EF(tn);

    // ---- E1 (swapped): C[outF][edge] = We1^T(+bias@k16) x ef^T ; relu+pack ----
    f16x2 pk[2][8][2];
    {
#pragma unroll
      for (int et = 0; et < 2; ++et) {
        f16x8 ae = zero8();
        if (kb < 2) ae = cvt8(efA[et][0], efA[et][1]);
        if (kb == 2) ae[0] = (f16)1.f;   // constant-1 feature at k=16 -> +be1
        const f32x4 z = {0.f, 0.f, 0.f, 0.f};
#pragma unroll
        for (int nt = 0; nt < 8; ++nt) {
          f16x8 w1f = read_b<6>(w1l, nt * 16 + c, kb * 16);
          f32x4 o = mfma16(w1f, ae, z);
          pk[et][nt][0] = pkrtz(fmaxf(o[0], 0.f), fmaxf(o[1], 0.f));
          pk[et][nt][1] = pkrtz(fmaxf(o[2], 0.f), fmaxf(o[3], 0.f));
        }
      }
    }

    // ---- P1: accp = bfold + h1e@WC + emb[src]@Wp1a + emb[dst]@Wp1b (all swapped) ----
    f32x4 accp[2][8];
#pragma unroll
    for (int nt = 0; nt < 8; ++nt) {
      f32x4 bv;
#pragma unroll
      for (int r = 0; r < 4; ++r) bv[r] = biasv[nt * 16 + kb * 4 + r];
      accp[0][nt] = bv;
      accp[1][nt] = bv;
    }
    // PE: pk-relabelled h1e fragments against k-permuted WC
#pragma unroll
    for (int ks = 0; ks < 4; ++ks) {
      f16x8 hb0 = frag4(pk[0][2*ks][0], pk[0][2*ks][1], pk[0][2*ks+1][0], pk[0][2*ks+1][1]);
      f16x8 hb1 = frag4(pk[1][2*ks][0], pk[1][2*ks][1], pk[1][2*ks+1][0], pk[1][2*ks+1][1]);
#pragma unroll
      for (int nt = 0; nt < 8; ++nt) {
        f16x8 bf = read_b<8>(wc, nt * 16 + c, ks * 64 + kb * 16);
        accp[0][nt] = mfma16(bf, hb0, accp[0][nt]);
        accp[1][nt] = mfma16(bf, hb1, accp[1][nt]);
      }
    }
    // P1a: gathered src rows (raw k) against plain Wp1a
#pragma unroll
    for (int ks = 0; ks < 4; ++ks)
#pragma unroll
      for (int nt = 0; nt < 8; ++nt) {
        f16x8 bf = read_b<8>(wa, nt * 16 + c, ks * 64 + kb * 16);
        accp[0][nt] = mfma16(bf, ga[0][ks], accp[0][nt]);
        accp[1][nt] = mfma16(bf, ga[1][ks], accp[1][nt]);
      }
    // P1b: gathered dst rows against plain Wp1b
#pragma unroll
    for (int ks = 0; ks < 4; ++ks)
#pragma unroll
      for (int nt = 0; nt < 8; ++nt) {
        f16x8 bf = read_b<8>(wb, nt * 16 + c, ks * 64 + kb * 16);
        accp[0][nt] = mfma16(bf, gb[0][ks], accp[0][nt]);
        accp[1][nt] = mfma16(bf, gb[1][ks], accp[1][nt]);
      }

    // ---- P1 -> P2 transition: relu + pack (register relabel) ----
    f16x2 qk[2][8][2];
#pragma unroll
    for (int et = 0; et < 2; ++et)
#pragma unroll
      for (int nt = 0; nt < 8; ++nt) {
        f32x4 o = accp[et][nt];
        qk[et][nt][0] = pkrtz(fmaxf(o[0], 0.f), fmaxf(o[1], 0.f));
        qk[et][nt][1] = pkrtz(fmaxf(o[2], 0.f), fmaxf(o[3], 0.f));
      }

    // ---- P2: accq = bp2 + relu(p1)@Wp2 (k-permuted wp2) ----
    f32x4 accq[2][4];
#pragma unroll
    for (int nt = 0; nt < 4; ++nt) {
      f32x4 bv;
#pragma unroll
      for (int r = 0; r < 4; ++r) bv[r] = biasv[128 + nt * 16 + kb * 4 + r];
      accq[0][nt] = bv;
      accq[1][nt] = bv;
    }
#pragma unroll
    for (int ks = 0; ks < 4; ++ks) {
      f16x8 qb0 = frag4(qk[0][2*ks][0], qk[0][2*ks][1], qk[0][2*ks+1][0], qk[0][2*ks+1][1]);
      f16x8 qb1 = frag4(qk[1][2*ks][0], qk[1][2*ks][1], qk[1][2*ks+1][0], qk[1][2*ks+1][1]);
#pragma unroll
      for (int nt = 0; nt < 4; ++nt) {
        f16x8 bf = read_b<8>(wp2l, nt * 16 + c, ks * 64 + kb * 16);
        accq[0][nt] = mfma16(bf, qb0, accq[0][nt]);
        accq[1][nt] = mfma16(bf, qb1, accq[1][nt]);
      }
    }

    // ---- P3: per-lane weighted sum over 16 held outF2, reduce across kb groups ----
#pragma unroll
    for (int et = 0; et < 2; ++et) {
      float s = 0.f;
#pragma unroll
      for (int nt = 0; nt < 4; ++nt) {
        f32x4 w3v;
#pragma unroll
        for (int r = 0; r < 4; ++r) w3v[r] = biasv[192 + nt * 16 + kb * 4 + r];
#pragma unroll
        for (int r = 0; r < 4; ++r) s += fmaxf(accq[et][nt][r], 0.f) * w3v[r];
      }
      s += __shfl_xor(s, 16, 64);
      s += __shfl_xor(s, 32, 64);
      if (lane < 16) {
        float v = 1.f / (1.f + __expf(-(s + b3)));
        __builtin_nontemporal_store(v, out + t * 32 + et * 16 + lane);
      }
    }
  }
}

extern "C" void kernel_launch(void* const* d_in, const int* in_sizes, int n_in,
                              void* d_out, int out_size, void* d_ws, size_t ws_size,
                              hipStream_t stream) {
  const float* nf  = (const float*)d_in[0];
  const int*   ei  = (const int*)  d_in[1];
  const float* ef  = (const float*)d_in[2];
  const float* Wn1 = (const float*)d_in[3];
  const float* bn1 = (const float*)d_in[4];
  const float* Wn2 = (const float*)d_in[5];
  const float* bn2 = (const float*)d_in[6];
  const float* We1 = (const float*)d_in[7];
  const float* be1 = (const float*)d_in[8];
  const float* We2 = (const float*)d_in[9];
  const float* be2 = (const float*)d_in[10];
  const float* Wp1 = (const float*)d_in[11];
  const float* bp1 = (const float*)d_in[12];
  const float* Wp2 = (const float*)d_in[13];
  const float* bp2 = (const float*)d_in[14];
  const float* Wp3 = (const float*)d_in[15];
  const float* bp3 = (const float*)d_in[16];

  char* ws = (char*)d_ws;
  f16*   WnT1  = (f16*)(ws);                 // 32768 B
  f16*   WnT2  = (f16*)(ws + 32768);         // 32768 B
  f16*   WeT1  = (f16*)(ws + 65536);         // 16384 B (128x32, bias@k16)
  f16*   WaT   = (f16*)(ws + 81920);         // 32768 B
  f16*   WbT   = (f16*)(ws + 114688);        // 32768 B
  f16*   WCT   = (f16*)(ws + 147456);        // 32768 B (k-permuted)
  f16*   WpT2  = (f16*)(ws + 180224);        // 16384 B (k-permuted)
  float* bfold = (float*)(ws + 196608);      // 512 B
  f16*   emb   = (f16*)(ws + 197120);        // 25,600,000 B

  prep_transpose<<<320, 256, 0, stream>>>(Wn1, Wn2, We1, be1, Wp1, Wp2,
                                          WnT1, WnT2, WeT1, WaT, WbT, WpT2);
  prep_fold<<<65, 256, 0, stream>>>(We2, Wp1, bp1, bn2, be2, WCT, bfold);
  node_kernel<<<782, 256, 0, stream>>>(nf, WnT1, bn1, WnT2, bn2, emb);
  edge_kernel<<<EK_BLOCKS, 512, 0, stream>>>(ef, ei, WeT1, WaT, WbT, WCT, WpT2,
                                             bfold, bp2, Wp3, bp3, emb, (float*)d_out);
}

// Round 9
// 637.633 us; speedup vs baseline: 1.0027x; 1.0027x over previous
//
#include <hip/hip_runtime.h>

typedef _Float16 f16;
typedef _Float16 f16x2 __attribute__((ext_vector_type(2)));
typedef _Float16 f16x4 __attribute__((ext_vector_type(4)));
typedef _Float16 f16x8 __attribute__((ext_vector_type(8)));
typedef __fp16   h16x2 __attribute__((ext_vector_type(2)));
typedef float    f32x4 __attribute__((ext_vector_type(4)));
typedef f16x8 f16x8_a __attribute__((may_alias));
typedef f16   f16_a   __attribute__((may_alias));

#define NN 100000
#define NE 1000000
#define NT_TILES 31250        // NE/32
#define EK_BLOCKS 256
#define NWAVES (EK_BLOCKS * 8)

static __device__ __forceinline__ f32x4 mfma16(f16x8 a, f16x8 b, f32x4 c) {
  return __builtin_amdgcn_mfma_f32_16x16x32_f16(a, b, c, 0, 0, 0);
}

static __device__ __forceinline__ f16x2 pkrtz(float a, float b) {
  h16x2 r = __builtin_amdgcn_cvt_pkrtz(a, b);
  return __builtin_bit_cast(f16x2, r);
}

static __device__ __forceinline__ f16x8 zero8() {
  f16x8 z;
#pragma unroll
  for (int j = 0; j < 8; ++j) z[j] = (f16)0.f;
  return z;
}

static __device__ __forceinline__ f16x8 cvt8(f32x4 x0, f32x4 x1) {
  f16x8 t;
  t[0]=(f16)x0[0]; t[1]=(f16)x0[1]; t[2]=(f16)x0[2]; t[3]=(f16)x0[3];
  t[4]=(f16)x1[0]; t[5]=(f16)x1[1]; t[6]=(f16)x1[2]; t[7]=(f16)x1[3];
  return t;
}

// assemble B-fragment from 4 packed f16x2 (register relabel, no data movement)
static __device__ __forceinline__ f16x8 frag4(f16x2 a, f16x2 b, f16x2 c, f16x2 d) {
  f16x4 lo = __builtin_shufflevector(a, b, 0, 1, 2, 3);
  f16x4 hi = __builtin_shufflevector(c, d, 0, 1, 2, 3);
  return __builtin_shufflevector(lo, hi, 0, 1, 2, 3, 4, 5, 6, 7);
}

// ---- LDS staging with XOR swizzle (byte ^= (row&7)<<4) ----
template<int RB_LOG2, int SZ, int NTH>
static __device__ __forceinline__ void load_weights(const f16* __restrict__ gw, char* lds) {
  const char* src = (const char*)gw;
#pragma unroll
  for (int g = threadIdx.x; g < SZ / 16; g += NTH) {
    int byte = g << 4;
    int row  = byte >> RB_LOG2;
    int dstb = byte ^ ((row & 7) << 4);
    f16x8 v = *(const f16x8_a*)(src + byte);
    *(f16x8_a*)(lds + dstb) = v;
  }
}

template<int RB_LOG2>
static __device__ __forceinline__ f16x8 read_b(const char* lds, int n, int kbyte) {
  int byte = ((n << RB_LOG2) + kbyte) ^ ((n & 7) << 4);
  return *(const f16x8_a*)(lds + byte);
}

// per-wave activation tile (node kernel only): 32 rows x 128 f16, swizzled
static __device__ __forceinline__ f16x8 act_read(const char* act, int base, int m, int kbyte) {
  int byte = (base + m * 256 + kbyte) ^ ((m & 7) << 4);
  return *(const f16x8_a*)(act + byte);
}

static __device__ __forceinline__ void act_write(char* act, int base, int m, int col, f16 v) {
  int byte = (base + m * 256 + col * 2) ^ ((m & 7) << 4);
  *(f16_a*)(act + byte) = v;
}

// K-permutation for pk-relabel consumers (wc, wp2): F = 32ks + 16a + 4g + b
static __device__ __forceinline__ int kperm(int kk) {
  return 32 * (kk >> 5) + 16 * ((kk >> 2) & 1) + 4 * ((kk >> 3) & 3) + (kk & 3);
}

// ---------------- prep kernels ----------------
__global__ void prep_transpose(const float* __restrict__ Wn1, const float* __restrict__ Wn2,
                               const float* __restrict__ We1, const float* __restrict__ be1,
                               const float* __restrict__ Wp1, const float* __restrict__ Wp2,
                               f16* __restrict__ WnT1, f16* __restrict__ WnT2,
                               f16* __restrict__ WeT1, f16* __restrict__ WaT,
                               f16* __restrict__ WbT,  f16* __restrict__ WpT2) {
  int b = blockIdx.x, t = threadIdx.x;
  if (b < 64)       { int i = b * 256 + t;         int n = i >> 7, k = i & 127; WnT1[i] = (f16)Wn1[(size_t)k * 128 + n]; }
  else if (b < 128) { int i = (b - 64) * 256 + t;  int n = i >> 7, k = i & 127; WnT2[i] = (f16)Wn2[(size_t)k * 128 + n]; }
  else if (b < 160) { int i = (b - 128) * 256 + t; int n = i >> 5, k = i & 31;
                      float v = k < 16 ? We1[(size_t)k * 128 + n] : (k == 16 ? be1[n] : 0.f);
                      WeT1[i] = (f16)v; }
  else if (b < 224) { int i = (b - 160) * 256 + t; int n = i >> 7, k = i & 127; WaT[i] = (f16)Wp1[(size_t)k * 128 + n]; }
  else if (b < 288) { int i = (b - 224) * 256 + t; int n = i >> 7, k = i & 127; WbT[i] = (f16)Wp1[(size_t)(128 + k) * 128 + n]; }
  else              { int i = (b - 288) * 256 + t; int n = i >> 7, kk = i & 127;
                      WpT2[i] = (f16)Wp2[(size_t)kperm(kk) * 64 + n]; }
}

// WC = We2 @ Wp1c (k-permuted, transposed), bfold = bp1 + bn2@(Wp1a+Wp1b) + be2@Wp1c
__global__ void prep_fold(const float* __restrict__ We2, const float* __restrict__ Wp1,
                          const float* __restrict__ bp1, const float* __restrict__ bn2,
                          const float* __restrict__ be2, f16* __restrict__ WCT,
                          float* __restrict__ bfold) {
  int b = blockIdx.x, t = threadIdx.x;
  if (b < 64) {
    int i = b * 256 + t;
    int n = i >> 7, kk = i & 127;
    int F = kperm(kk);
    float s = 0.f;
#pragma unroll 8
    for (int m = 0; m < 128; ++m)
      s += We2[(size_t)F * 128 + m] * Wp1[(size_t)(256 + m) * 128 + n];
    WCT[i] = (f16)s;
  } else if (t < 128) {
    float s = bp1[t];
#pragma unroll 8
    for (int k = 0; k < 128; ++k)
      s += bn2[k] * (Wp1[(size_t)k * 128 + t] + Wp1[(size_t)(128 + k) * 128 + t]);
#pragma unroll 8
    for (int k = 0; k < 128; ++k)
      s += be2[k] * Wp1[(size_t)(256 + k) * 128 + t];
    bfold[t] = s;
  }
}

// ---------------- node encoder: nf -> relu(@Wn1+bn1) -> @Wn2+bn2 -> emb (f16) ----------------
__global__ __launch_bounds__(256, 2) void node_kernel(
    const float* __restrict__ nf, const f16* __restrict__ WnT1, const float* __restrict__ bn1,
    const f16* __restrict__ WnT2, const float* __restrict__ bn2, f16* __restrict__ emb) {
  __shared__ char wbuf[32768];
  __shared__ char act[32768];
  const int tid = threadIdx.x, w = tid >> 6, lane = tid & 63;
  const int c = lane & 15, kb = lane >> 4;
  const int base = blockIdx.x * 128 + w * 32;
  const int abase = w * 8192;

  load_weights<8, 32768, 256>(WnT1, wbuf);
  __syncthreads();

  {
    f16x8 a[2][4];
#pragma unroll
    for (int rt = 0; rt < 2; ++rt) {
      int r = base + rt * 16 + c; r = r < NN ? r : 0;
      const f32x4* p = (const f32x4*)(nf + (size_t)r * 128 + kb * 8);
#pragma unroll
      for (int ks = 0; ks < 4; ++ks) {
        f32x4 x0 = __builtin_nontemporal_load(p + ks * 8);
        f32x4 x1 = __builtin_nontemporal_load(p + ks * 8 + 1);
        a[rt][ks] = cvt8(x0, x1);
      }
    }
    f32x4 acc[2][8];
#pragma unroll
    for (int nt = 0; nt < 8; ++nt) {
      float bb = bn1[nt * 16 + c];
      acc[0][nt] = f32x4{bb, bb, bb, bb};
      acc[1][nt] = f32x4{bb, bb, bb, bb};
    }
#pragma unroll
    for (int ks = 0; ks < 4; ++ks)
#pragma unroll
      for (int nt = 0; nt < 8; ++nt) {
        f16x8 b = read_b<8>(wbuf, nt * 16 + c, ks * 64 + kb * 16);
        acc[0][nt] = mfma16(a[0][ks], b, acc[0][nt]);
        acc[1][nt] = mfma16(a[1][ks], b, acc[1][nt]);
      }
#pragma unroll
    for (int rt = 0; rt < 2; ++rt)
#pragma unroll
      for (int nt = 0; nt < 8; ++nt)
#pragma unroll
        for (int r = 0; r < 4; ++r) {
          float v = acc[rt][nt][r];
          v = v > 0.f ? v : 0.f;
          act_write(act, abase, rt * 16 + kb * 4 + r, nt * 16 + c, (f16)v);
        }
  }

  __syncthreads();
  load_weights<8, 32768, 256>(WnT2, wbuf);
  __syncthreads();

  {
    f32x4 acc[2][8];
#pragma unroll
    for (int nt = 0; nt < 8; ++nt) {
      float bb = bn2[nt * 16 + c];
      acc[0][nt] = f32x4{bb, bb, bb, bb};
      acc[1][nt] = f32x4{bb, bb, bb, bb};
    }
#pragma unroll
    for (int ks = 0; ks < 4; ++ks) {
      f16x8 a0 = act_read(act, abase, c,      ks * 64 + kb * 16);
      f16x8 a1 = act_read(act, abase, 16 + c, ks * 64 + kb * 16);
#pragma unroll
      for (int nt = 0; nt < 8; ++nt) {
        f16x8 b = read_b<8>(wbuf, nt * 16 + c, ks * 64 + kb * 16);
        acc[0][nt] = mfma16(a0, b, acc[0][nt]);
        acc[1][nt] = mfma16(a1, b, acc[1][nt]);
      }
    }
#pragma unroll
    for (int rt = 0; rt < 2; ++rt)
#pragma unroll
      for (int nt = 0; nt < 8; ++nt)
#pragma unroll
        for (int r = 0; r < 4; ++r) {
          int row = base + rt * 16 + kb * 4 + r;
          if (row < NN) emb[(size_t)row * 128 + nt * 16 + c] = (f16)acc[rt][nt][r];
        }
  }
}

// ---------------- persistent fused edge kernel: swapped MFMA, register-chained ----------------
// __launch_bounds__(512, 1): an 8-wave block must fit 2 waves/SIMD -> VGPR cap 256.
// (512, 2) made the compiler target 128 VGPR and SPILL (R6: FETCH +450MB of scratch).
__global__ __launch_bounds__(512, 1) void edge_kernel(
    const float* __restrict__ ef, const int* __restrict__ eidx,
    const f16* __restrict__ We1g, const f16* __restrict__ WaTg,
    const f16* __restrict__ WbTg, const f16* __restrict__ WCTg,
    const f16* __restrict__ Wp2Tg, const float* __restrict__ bfold,
    const float* __restrict__ bp2, const float* __restrict__ Wp3,
    const float* __restrict__ bp3, const f16* __restrict__ emb,
    float* __restrict__ out) {
  __shared__ char wa[32768];
  __shared__ char wb[32768];
  __shared__ char wc[32768];
  __shared__ char wp2l[16384];
  __shared__ char w1l[8192];
  __shared__ float biasl[256];   // [0:128) bfold, [128:192) bp2, [192:256) Wp3
  const int tid = threadIdx.x, w = tid >> 6, lane = tid & 63;
  const int c = lane & 15, kb = lane >> 4;

  load_weights<8, 32768, 512>(WaTg, wa);
  load_weights<8, 32768, 512>(WbTg, wb);
  load_weights<8, 32768, 512>(WCTg, wc);
  load_weights<8, 16384, 512>(Wp2Tg, wp2l);
  load_weights<6, 8192, 512>(We1g, w1l);
  if (tid < 256) {
    float v = tid < 128 ? bfold[tid] : (tid < 192 ? bp2[tid - 128] : Wp3[tid - 192]);
    biasl[tid] = v;
  }
  __syncthreads();   // only barrier

  const float b3 = bp3[0];
  const int gw = blockIdx.x * 8 + w;
  const volatile float* biasv = biasl;

  int sN[2], dN[2];
  f32x4 efN[2][2];

  auto LOAD_IDX = [&](int t) {
#pragma unroll
    for (int et = 0; et < 2; ++et) {
      sN[et] = __builtin_nontemporal_load(eidx + t * 32 + et * 16 + c);
      dN[et] = __builtin_nontemporal_load(eidx + NE + t * 32 + et * 16 + c);
    }
  };
  auto LOAD_EF = [&](int t) {
    if (kb < 2) {
#pragma unroll
      for (int et = 0; et < 2; ++et) {
        const f32x4* p = (const f32x4*)(ef + (size_t)(t * 32 + et * 16 + c) * 16 + kb * 8);
        efN[et][0] = __builtin_nontemporal_load(p);
        efN[et][1] = __builtin_nontemporal_load(p + 1);
      }
    }
  };

  if (gw < NT_TILES) { LOAD_IDX(gw); LOAD_EF(gw); }

  for (int t = gw; t < NT_TILES; t += NWAVES) {
    const int sA0 = sN[0], sA1 = sN[1], dA0 = dN[0], dA1 = dN[1];
    f32x4 efA[2][2] = {{efN[0][0], efN[0][1]}, {efN[1][0], efN[1][1]}};

    // issue this tile's gathers (consumed at P1a/P1b, ~80 MFMAs later)
    f16x8 ga[2][4], gb[2][4];
    {
      const f16* p0 = emb + (size_t)sA0 * 128 + kb * 8;
      const f16* p1 = emb + (size_t)sA1 * 128 + kb * 8;
      const f16* q0 = emb + (size_t)dA0 * 128 + kb * 8;
      const f16* q1 = emb + (size_t)dA1 * 128 + kb * 8;
#pragma unroll
      for (int ks = 0; ks < 4; ++ks) {
        ga[0][ks] = *(const f16x8_a*)(p0 + ks * 32);
        ga[1][ks] = *(const f16x8_a*)(p1 + ks * 32);
        gb[0][ks] = *(const f16x8_a*)(q0 + ks * 32);
        gb[1][ks] = *(const f16x8_a*)(q1 + ks * 32);
      }
    }

    // prefetch next tile's idx + ef
    int tn = t + NWAVES; if (tn >= NT_TILES) tn = t;
    LOAD_IDX(tn);
    LOAD_EF(tn);

    // ---- E1 (swapped): C[outF][edge] = We1^T(+bias@k16) x ef^T ; relu+pack ----
    f16x2 pk[2][8][2];
    {
#pragma unroll
      for (int et = 0; et < 2; ++et) {
        f16x8 ae = zero8();
        if (kb < 2) ae = cvt8(efA[et][0], efA[et][1]);
        if (kb == 2) ae[0] = (f16)1.f;   // constant-1 feature at k=16 -> +be1
        const f32x4 z = {0.f, 0.f, 0.f, 0.f};
#pragma unroll
        for (int nt = 0; nt < 8; ++nt) {
          f16x8 w1f = read_b<6>(w1l, nt * 16 + c, kb * 16);
          f32x4 o = mfma16(w1f, ae, z);
          pk[et][nt][0] = pkrtz(fmaxf(o[0], 0.f), fmaxf(o[1], 0.f));
          pk[et][nt][1] = pkrtz(fmaxf(o[2], 0.f), fmaxf(o[3], 0.f));
        }
      }
    }

    // ---- P1: accp = bfold + h1e@WC + emb[src]@Wp1a + emb[dst]@Wp1b (all swapped) ----
    f32x4 accp[2][8];
#pragma unroll
    for (int nt = 0; nt < 8; ++nt) {
      f32x4 bv;
#pragma unroll
      for (int r = 0; r < 4; ++r) bv[r] = biasv[nt * 16 + kb * 4 + r];
      accp[0][nt] = bv;
      accp[1][nt] = bv;
    }
    // PE: pk-relabelled h1e fragments against k-permuted WC
#pragma unroll
    for (int ks = 0; ks < 4; ++ks) {
      f16x8 hb0 = frag4(pk[0][2*ks][0], pk[0][2*ks][1], pk[0][2*ks+1][0], pk[0][2*ks+1][1]);
      f16x8 hb1 = frag4(pk[1][2*ks][0], pk[1][2*ks][1], pk[1][2*ks+1][0], pk[1][2*ks+1][1]);
#pragma unroll
      for (int nt = 0; nt < 8; ++nt) {
        f16x8 bf = read_b<8>(wc, nt * 16 + c, ks * 64 + kb * 16);
        accp[0][nt] = mfma16(bf, hb0, accp[0][nt]);
        accp[1][nt] = mfma16(bf, hb1, accp[1][nt]);
      }
    }
    // P1a: gathered src rows (raw k) against plain Wp1a
#pragma unroll
    for (int ks = 0; ks < 4; ++ks)
#pragma unroll
      for (int nt = 0; nt < 8; ++nt) {
        f16x8 bf = read_b<8>(wa, nt * 16 + c, ks * 64 + kb * 16);
        accp[0][nt] = mfma16(bf, ga[0][ks], accp[0][nt]);
        accp[1][nt] = mfma16(bf, ga[1][ks], accp[1][nt]);
      }
    // P1b: gathered dst rows against plain Wp1b
#pragma unroll
    for (int ks = 0; ks < 4; ++ks)
#pragma unroll
      for (int nt = 0; nt < 8; ++nt) {
        f16x8 bf = read_b<8>(wb, nt * 16 + c, ks * 64 + kb * 16);
        accp[0][nt] = mfma16(bf, gb[0][ks], accp[0][nt]);
        accp[1][nt] = mfma16(bf, gb[1][ks], accp[1][nt]);
      }

    // ---- P1 -> P2 transition: relu + pack (register relabel) ----
    f16x2 qk[2][8][2];
#pragma unroll
    for (int et = 0; et < 2; ++et)
#pragma unroll
      for (int nt = 0; nt < 8; ++nt) {
        f32x4 o = accp[et][nt];
        qk[et][nt][0] = pkrtz(fmaxf(o[0], 0.f), fmaxf(o[1], 0.f));
        qk[et][nt][1] = pkrtz(fmaxf(o[2], 0.f), fmaxf(o[3], 0.f));
      }

    // ---- P2: accq = bp2 + relu(p1)@Wp2 (k-permuted wp2) ----
    f32x4 accq[2][4];
#pragma unroll
    for (int nt = 0; nt < 4; ++nt) {
      f32x4 bv;
#pragma unroll
      for (int r = 0; r < 4; ++r) bv[r] = biasv[128 + nt * 16 + kb * 4 + r];
      accq[0][nt] = bv;
      accq[1][nt] = bv;
    }
#pragma unroll
    for (int ks = 0; ks < 4; ++ks) {
      f16x8 qb0 = frag4(qk[0][2*ks][0], qk[0][2*ks][1], qk[0][2*ks+1][0], qk[0][2*ks+1][1]);
      f16x8 qb1 = frag4(qk[1][2*ks][0], qk[1][2*ks][1], qk[1][2*ks+1][0], qk[1][2*ks+1][1]);
#pragma unroll
      for (int nt = 0; nt < 4; ++nt) {
        f16x8 bf = read_b<8>(wp2l, nt * 16 + c, ks * 64 + kb * 16);
        accq[0][nt] = mfma16(bf, qb0, accq[0][nt]);
        accq[1][nt] = mfma16(bf, qb1, accq[1][nt]);
      }
    }

    // ---- P3: per-lane weighted sum over 16 held outF2, reduce across kb groups ----
#pragma unroll
    for (int et = 0; et < 2; ++et) {
      float s = 0.f;
#pragma unroll
      for (int nt = 0; nt < 4; ++nt) {
        f32x4 w3v;
#pragma unroll
        for (int r = 0; r < 4; ++r) w3v[r] = biasv[192 + nt * 16 + kb * 4 + r];
#pragma unroll
        for (int r = 0; r < 4; ++r) s += fmaxf(accq[et][nt][r], 0.f) * w3v[r];
      }
      s += __shfl_xor(s, 16, 64);
      s += __shfl_xor(s, 32, 64);
      if (lane < 16) {
        float v = 1.f / (1.f + __expf(-(s + b3)));
        __builtin_nontemporal_store(v, out + t * 32 + et * 16 + lane);
      }
    }
  }
}

extern "C" void kernel_launch(void* const* d_in, const int* in_sizes, int n_in,
                              void* d_out, int out_size, void* d_ws, size_t ws_size,
                              hipStream_t stream) {
  const float* nf  = (const float*)d_in[0];
  const int*   ei  = (const int*)  d_in[1];
  const float* ef  = (const float*)d_in[2];
  const float* Wn1 = (const float*)d_in[3];
  const float* bn1 = (const float*)d_in[4];
  const float* Wn2 = (const float*)d_in[5];
  const float* bn2 = (const float*)d_in[6];
  const float* We1 = (const float*)d_in[7];
  const float* be1 = (const float*)d_in[8];
  const float* We2 = (const float*)d_in[9];
  const float* be2 = (const float*)d_in[10];
  const float* Wp1 = (const float*)d_in[11];
  const float* bp1 = (const float*)d_in[12];
  const float* Wp2 = (const float*)d_in[13];
  const float* bp2 = (const float*)d_in[14];
  const float* Wp3 = (const float*)d_in[15];
  const float* bp3 = (const float*)d_in[16];

  char* ws = (char*)d_ws;
  f16*   WnT1  = (f16*)(ws);                 // 32768 B
  f16*   WnT2  = (f16*)(ws + 32768);         // 32768 B
  f16*   WeT1  = (f16*)(ws + 65536);         // 16384 B (128x32, bias@k16)
  f16*   WaT   = (f16*)(ws + 81920);         // 32768 B
  f16*   WbT   = (f16*)(ws + 114688);        // 32768 B
  f16*   WCT   = (f16*)(ws + 147456);        // 32768 B (k-permuted)
  f16*   WpT2  = (f16*)(ws + 180224);        // 16384 B (k-permuted)
  float* bfold = (float*)(ws + 196608);      // 512 B
  f16*   emb   = (f16*)(ws + 197120);        // 25,600,000 B

  prep_transpose<<<320, 256, 0, stream>>>(Wn1, Wn2, We1, be1, Wp1, Wp2,
                                          WnT1, WnT2, WeT1, WaT, WbT, WpT2);
  prep_fold<<<65, 256, 0, stream>>>(We2, Wp1, bp1, bn2, be2, WCT, bfold);
  node_kernel<<<782, 256, 0, stream>>>(nf, WnT1, bn1, WnT2, bn2, emb);
  edge_kernel<<<EK_BLOCKS, 512, 0, stream>>>(ef, ei, WeT1, WaT, WbT, WCT, WpT2,
                                             bfold, bp2, Wp3, bp3, emb, (float*)d_out);
}